// Round 7
// baseline (177.417 us; speedup 1.0000x reference)
//
#include <hip/hip_runtime.h>

// SimAttn: out = softmax(1000*softmax(QK^T/sqrt(dk))) @ V, fp32 I/O.
// v7 = v6 skeleton (pre-converted f16 K / transposed V in d_ws, KB=32 chunks,
// global_load_lds width-16 staging, double-buffered, one barrier/chunk) plus:
//   - w-tile LDS round-trip replaced by 8 __shfl + 4 cndmask (conflict-free,
//     frees 4KB LDS -> 32768B -> 5 blocks/CU).
//   - all exps in exp2 domain (__builtin_amdgcn_exp2f; saves the v_mul inside
//     __expf). p/pm bit-identity preserved -> max w-exponent exactly 0.
// pass 1: f16 QK^T -> row max m, l8 = sum 2^(s*SC2-MOFF2)
// pass 2: identical scores -> p = 2^(s*SC2-MOFF2), w = 2^(fmaf(p, ul2, mcu2)),
//         ul2 = (1000/l8)*log2e, mcu2 = -ul2*pm; PV f16 MFMA; /= sum(w).

typedef __attribute__((ext_vector_type(4))) float f32x4;
typedef __attribute__((ext_vector_type(8))) _Float16 h16x8;
typedef __attribute__((ext_vector_type(4))) _Float16 h16x4;
typedef __attribute__((ext_vector_type(8))) short s16x8;
typedef __attribute__((ext_vector_type(4))) short s16x4;
typedef __attribute__((ext_vector_type(2))) unsigned int u32x2;
typedef __attribute__((ext_vector_type(4))) unsigned int u32x4;

#define NB 4
#define T_ 2048
#define D_ 1024
#define NH 8
#define DK 128
#define BQ 64
#define NWG (NB * NH * (T_ / BQ))  // 1024
#define KB2 32
#define NKC2 (T_ / KB2)            // 64
#define SCALE 0.08838834764831845f // 1/sqrt(128)
#define SC2   0.12751741689839996f // SCALE * log2(e)
#define MOFF2 11.541560327111707f  // 8 * log2(e)
#define L2E   1.4426950408889634f

__device__ __forceinline__ unsigned int pk2(float a, float b) {
  return __builtin_bit_cast(unsigned int, __builtin_amdgcn_cvt_pkrtz(a, b));
}
#define H8(p) __builtin_bit_cast(h16x8, *(const s16x8*)(p))

__device__ __forceinline__ void gload16(const unsigned short* g, unsigned short* l) {
  __builtin_amdgcn_global_load_lds(
      (const __attribute__((address_space(1))) void*)g,
      (__attribute__((address_space(3))) void*)l, 16, 0, 0);
}

// ---- pre-kernel 1: K fp32 [b][k][h*128+d] -> f16 K16[(b*8+h)][k][d] --------
__global__ __launch_bounds__(256) void cvtK16(const float* __restrict__ Kg,
                                              unsigned short* __restrict__ K16) {
  const int t = threadIdx.x;
#pragma unroll
  for (int i = 0; i < 4; ++i) {
    const unsigned gid = blockIdx.x * 1024u + i * 256u + t;
    const unsigned bhk = gid >> 4, dg = gid & 15u;
    const unsigned b = bhk >> 14, rem = bhk & 16383u;
    const unsigned h = rem >> 11, k = rem & 2047u;
    const float* s = Kg + ((size_t)b * T_ + k) * D_ + h * DK + dg * 8;
    f32x4 x0 = *(const f32x4*)s, x1 = *(const f32x4*)(s + 4);
    h16x8 hv;
#pragma unroll
    for (int j = 0; j < 4; ++j) { hv[j] = (_Float16)x0[j]; hv[j + 4] = (_Float16)x1[j]; }
    *(u32x4*)(K16 + (size_t)gid * 8) = __builtin_bit_cast(u32x4, hv);
  }
}

// ---- pre-kernel 2: V fp32 -> f16 transposed V16t[(b*8+h)][d][k] ------------
__global__ __launch_bounds__(256) void trV16(const float* __restrict__ Vg,
                                             unsigned short* __restrict__ V16t) {
  __shared__ float vt[64][129];
  const int t = threadIdx.x;
  const int bh = blockIdx.x >> 5;
  const int kc = blockIdx.x & 31;
  const int b = bh >> 3, h = bh & 7;
  const float* src = Vg + ((size_t)b * T_ + kc * 64) * D_ + h * DK;
#pragma unroll
  for (int p = 0; p < 8; ++p) {
    const int j = t + p * 256;
    const int row = j >> 5, c4 = j & 31;
    f32x4 v = *(const f32x4*)(src + (size_t)row * D_ + c4 * 4);
#pragma unroll
    for (int i = 0; i < 4; ++i) vt[row][c4 * 4 + i] = v[i];
  }
  __syncthreads();
  unsigned short* dst = V16t + (size_t)bh * DK * T_ + (size_t)kc * 64;
#pragma unroll
  for (int i = 0; i < 4; ++i) {
    const int gg = t + i * 256;
    const int d = gg >> 3, kg = gg & 7;
    u32x4 pv;
#pragma unroll
    for (int jj = 0; jj < 4; ++jj)
      pv[jj] = pk2(vt[kg * 8 + 2 * jj][d], vt[kg * 8 + 2 * jj + 1][d]);
    *(u32x4*)(dst + (size_t)d * T_ + kg * 8) = pv;
  }
}

// ---- main kernel -----------------------------------------------------------
__global__ __launch_bounds__(256, 4) void simattn_v7(
    const float* __restrict__ Qg, const unsigned short* __restrict__ K16,
    const unsigned short* __restrict__ V16t, float* __restrict__ Og) {
  __shared__ __align__(16) unsigned short kf[2][KB2 * DK];   // 16 KB
  __shared__ __align__(16) unsigned short vts[2][DK * KB2];  // 16 KB

  const int tid  = threadIdx.x;
  const int wid  = tid >> 6;
  const int lane = tid & 63;
  const int lr   = lane & 15;
  const int lg   = lane >> 4;

  // XCD-chunked swizzle (1024 % 8 == 0 -> simple bijection)
  const int blk  = (blockIdx.x & 7) * (NWG >> 3) + (blockIdx.x >> 3);
  const int qblk = blk & (T_ / BQ - 1);
  const int h    = (blk >> 5) & (NH - 1);
  const int b    = blk >> 8;
  const int q0   = qblk * BQ;
  const size_t bh  = (size_t)b * (T_ * D_) + (size_t)h * DK;  // fp32 panels
  const int    bhp = b * NH + h;                              // f16 panel idx
  const unsigned short* kp16 = K16 + (size_t)bhp * (T_ * DK);
  const unsigned short* vp16 = V16t + (size_t)bhp * (DK * T_);

  // ---- Q fragments (f16, RNE), kept in registers ---------------------------
  h16x8 qf[4];
  {
    const float* qp = Qg + bh + (size_t)(q0 + wid * 16 + lr) * D_;
#pragma unroll
    for (int s = 0; s < 4; ++s) {
      const int d0 = s * 32 + lg * 8;
      f32x4 x0 = *(const f32x4*)(qp + d0);
      f32x4 x1 = *(const f32x4*)(qp + d0 + 4);
#pragma unroll
      for (int i = 0; i < 4; ++i) {
        qf[s][i]     = (_Float16)x0[i];
        qf[s][i + 4] = (_Float16)x1[i];
      }
    }
  }

  // ---- per-lane staging source offsets (elements), chunk-invariant ---------
  int koffs[2], voffs[2];
  const int kdst0 = wid * 1024;
#pragma unroll
  for (int i = 0; i < 2; ++i) {
    const int id = wid * 2 + i;
    {
      const int r = id * 4 + (lane >> 4), gL = lane & 15;
      koffs[i] = r * DK + ((gL ^ (r & 7)) * 8);
    }
    {
      const int d = id * 16 + (lane >> 2), s = lane & 3;
      voffs[i] = d * T_ + ((s ^ ((d >> 1) & 3)) * 8);
    }
  }
  auto stK = [&](int kc, int buf) {
    const unsigned short* s0 = kp16 + (size_t)kc * (KB2 * DK);
    gload16(s0 + koffs[0], &kf[buf][kdst0]);
    gload16(s0 + koffs[1], &kf[buf][kdst0 + 512]);
  };
  auto stV = [&](int kc, int buf) {
    const unsigned short* s0 = vp16 + kc * KB2;
    gload16(s0 + voffs[0], &vts[buf][kdst0]);
    gload16(s0 + voffs[1], &vts[buf][kdst0 + 512]);
  };

  // Swapped QK^T (KB2=32): st[nt][r] = S[k = nt*16 + lg*4 + r][q = lr]
  auto qkT = [&](int buf, f32x4* st) {
    st[0] = (f32x4){0.f, 0.f, 0.f, 0.f};
    st[1] = (f32x4){0.f, 0.f, 0.f, 0.f};
#pragma unroll
    for (int s = 0; s < 4; ++s) {
#pragma unroll
      for (int nt = 0; nt < 2; ++nt) {
        const int kr = nt * 16 + lr;
        const int eg = ((4 * s + lg) ^ (kr & 7)) * 8;
        st[nt] = __builtin_amdgcn_mfma_f32_16x16x32_f16(
            H8(&kf[buf][kr * DK + eg]), qf[s], st[nt], 0, 0, 0);
      }
    }
  };

  // ---- pass 1: per-q max + l8 = sum 2^(s*SC2 - MOFF2) ----------------------
  float msc = -3.0e38f, l8 = 0.f;
  stK(0, 0);
  __syncthreads();
  for (int kc = 0; kc < NKC2; ++kc) {
    if (kc + 1 < NKC2) stK(kc + 1, (kc + 1) & 1);
    f32x4 st[2];
    qkT(kc & 1, st);
    float e[8];
#pragma unroll
    for (int nt = 0; nt < 2; ++nt) {
#pragma unroll
      for (int r = 0; r < 4; ++r) {
        const float s = st[nt][r];
        msc = fmaxf(msc, s);
        e[nt * 4 + r] = __builtin_amdgcn_exp2f(fmaf(s, SC2, -MOFF2));
      }
    }
    l8 += ((e[0] + e[1]) + (e[2] + e[3])) + ((e[4] + e[5]) + (e[6] + e[7]));
    __syncthreads();
  }
  msc = fmaxf(msc, __shfl_xor(msc, 16));
  msc = fmaxf(msc, __shfl_xor(msc, 32));
  l8 += __shfl_xor(l8, 16);
  l8 += __shfl_xor(l8, 32);
  const float pm   = __builtin_amdgcn_exp2f(fmaf(msc, SC2, -MOFF2)); // = max p
  const float ul2  = (1000.0f / l8) * L2E;
  const float mcu2 = -ul2 * pm;

  // ---- pass 2: scores -> w (regs, shuffled) -> PV --------------------------
  f32x4 y[8];
#pragma unroll
  for (int dt = 0; dt < 8; ++dt) y[dt] = (f32x4){0.f, 0.f, 0.f, 0.f};
  float Wl = 0.f;
  const int src0 = lr + 32 * (lg & 1);  // w providers for af dwords 0,1
  const int src1 = src0 + 16;           // ... dwords 2,3
  const bool ntv = (lg >> 1) != 0;

  stK(0, 0);
  stV(0, 0);
  __syncthreads();
  for (int kc = 0; kc < NKC2; ++kc) {
    if (kc + 1 < NKC2) { stK(kc + 1, (kc + 1) & 1); stV(kc + 1, (kc + 1) & 1); }
    const int buf = kc & 1;
    f32x4 st[2];
    qkT(buf, st);  // bitwise-identical to pass 1

    // weights for q = lr, k = nt*16 + lg*4 + r; pack adjacent-k pairs
    unsigned pkv[2][2];
#pragma unroll
    for (int nt = 0; nt < 2; ++nt) {
      float w[4];
#pragma unroll
      for (int r = 0; r < 4; ++r) {
        const float pp = __builtin_amdgcn_exp2f(fmaf(st[nt][r], SC2, -MOFF2));
        w[r] = __builtin_amdgcn_exp2f(fmaf(pp, ul2, mcu2));
      }
      Wl += (w[0] + w[1]) + (w[2] + w[3]);
      pkv[nt][0] = pk2(w[0], w[1]);
      pkv[nt][1] = pk2(w[2], w[3]);
    }

    // redistribute C/D-layout w -> A-frag via shuffles (no LDS):
    // af[i] = pkv[lg>>1][i&1] taken from lane lr + 32*(lg&1) + 16*(i>>1)
    const unsigned a0 = (unsigned)__shfl((int)pkv[0][0], src0);
    const unsigned b0 = (unsigned)__shfl((int)pkv[1][0], src0);
    const unsigned a1 = (unsigned)__shfl((int)pkv[0][1], src0);
    const unsigned b1 = (unsigned)__shfl((int)pkv[1][1], src0);
    const unsigned a2 = (unsigned)__shfl((int)pkv[0][0], src1);
    const unsigned b2 = (unsigned)__shfl((int)pkv[1][0], src1);
    const unsigned a3 = (unsigned)__shfl((int)pkv[0][1], src1);
    const unsigned b3 = (unsigned)__shfl((int)pkv[1][1], src1);
    u32x4 aw;
    aw[0] = ntv ? b0 : a0;
    aw[1] = ntv ? b1 : a1;
    aw[2] = ntv ? b2 : a2;
    aw[3] = ntv ? b3 : a3;
    const h16x8 af = __builtin_bit_cast(h16x8, aw);

    // PV: A = shuffled w (k = lg*8 + e), B = V^T tile.
#pragma unroll
    for (int dt = 0; dt < 8; ++dt) {
      const int d = dt * 16 + lr;
      const int sv = lg ^ ((d >> 1) & 3);
      y[dt] = __builtin_amdgcn_mfma_f32_16x16x32_f16(
          af, H8(&vts[buf][d * KB2 + sv * 8]), y[dt], 0, 0, 0);
    }
    __syncthreads();
  }

  // ---- normalize and store -------------------------------------------------
  Wl += __shfl_xor(Wl, 16);
  Wl += __shfl_xor(Wl, 32);
  const float winv = 1.0f / Wl;  // valid for q = lr

  float* op = Og + bh + (size_t)(q0 + wid * 16) * D_;
#pragma unroll
  for (int r = 0; r < 4; ++r) {
    const float wv = __shfl(winv, lg * 4 + r);
#pragma unroll
    for (int dt = 0; dt < 8; ++dt) {
      op[(size_t)(lg * 4 + r) * D_ + dt * 16 + lr] = y[dt][r] * wv;
    }
  }
}

// ---- fallback: R3-style kernel (used when ws_size is too small) ------------
__global__ __launch_bounds__(256, 4) void simattn_fb(
    const float* __restrict__ Qg, const float* __restrict__ Kg,
    const float* __restrict__ Vg, float* __restrict__ Og) {
  __shared__ __align__(16) unsigned short kfb[64][DK];
  __shared__ __align__(16) unsigned short vtb[DK][64];
  __shared__ __align__(16) unsigned int   wlb[4][16][32];

  const int tid  = threadIdx.x;
  const int wid  = tid >> 6;
  const int lane = tid & 63;
  const int lr   = lane & 15;
  const int lg   = lane >> 4;

  const int blk  = blockIdx.x;
  const int qblk = blk & (T_ / BQ - 1);
  const int h    = (blk >> 5) & (NH - 1);
  const int b    = blk >> 8;
  const int q0   = qblk * BQ;
  const size_t bh = (size_t)b * (T_ * D_) + (size_t)h * DK;

  h16x8 qf[4];
  {
    const float* qp = Qg + bh + (size_t)(q0 + wid * 16 + lr) * D_;
#pragma unroll
    for (int s = 0; s < 4; ++s) {
      const int d0 = s * 32 + lg * 8;
      f32x4 x0 = *(const f32x4*)(qp + d0);
      f32x4 x1 = *(const f32x4*)(qp + d0 + 4);
#pragma unroll
      for (int i = 0; i < 4; ++i) { qf[s][i] = (_Float16)x0[i]; qf[s][i+4] = (_Float16)x1[i]; }
    }
  }
  auto stageK = [&](int kc) {
    const float* kp = Kg + bh + (size_t)kc * 64 * D_;
#pragma unroll
    for (int p = 0; p < 8; ++p) {
      const int j = tid + p * 256;
      const int row = j >> 5, c4 = j & 31;
      f32x4 v = *(const f32x4*)(kp + (size_t)row * D_ + c4 * 4);
      h16x4 hv;
#pragma unroll
      for (int i = 0; i < 4; ++i) hv[i] = (_Float16)v[i];
      const int e = (c4 * 4) ^ ((row & 7) << 3);
      *(s16x4*)&kfb[row][e] = __builtin_bit_cast(s16x4, hv);
    }
  };
  auto qkT = [&](f32x4* st) {
#pragma unroll
    for (int nt = 0; nt < 4; ++nt) st[nt] = (f32x4){0.f, 0.f, 0.f, 0.f};
#pragma unroll
    for (int s = 0; s < 4; ++s) {
#pragma unroll
      for (int nt = 0; nt < 4; ++nt) {
        const int kr = nt * 16 + lr;
        const int e = (s * 32 + lg * 8) ^ ((kr & 7) << 3);
        st[nt] = __builtin_amdgcn_mfma_f32_16x16x32_f16(H8(&kfb[kr][e]), qf[s], st[nt], 0, 0, 0);
      }
    }
  };
  float msc = -3.0e38f, l8 = 0.f;
  for (int kc = 0; kc < 32; ++kc) {
    __syncthreads();
    stageK(kc);
    __syncthreads();
    f32x4 st[4];
    qkT(st);
#pragma unroll
    for (int nt = 0; nt < 4; ++nt)
#pragma unroll
      for (int r = 0; r < 4; ++r) {
        const float s = st[nt][r];
        msc = fmaxf(msc, s);
        l8 += __builtin_amdgcn_exp2f(fmaf(s, SC2, -MOFF2));
      }
  }
  msc = fmaxf(msc, __shfl_xor(msc, 16));
  msc = fmaxf(msc, __shfl_xor(msc, 32));
  l8 += __shfl_xor(l8, 16);
  l8 += __shfl_xor(l8, 32);
  const float pm   = __builtin_amdgcn_exp2f(fmaf(msc, SC2, -MOFF2));
  const float ul2  = (1000.0f / l8) * L2E;
  const float mcu2 = -ul2 * pm;

  f32x4 y[8];
#pragma unroll
  for (int dt = 0; dt < 8; ++dt) y[dt] = (f32x4){0.f, 0.f, 0.f, 0.f};
  float Wl = 0.f;
  const int dv  = tid & 127;
  const int kg0 = tid >> 7;
  for (int kc = 0; kc < 32; ++kc) {
    __syncthreads();
    stageK(kc);
    {
      const float* vp = Vg + bh + (size_t)kc * 64 * D_ + dv;
#pragma unroll
      for (int i = 0; i < 4; ++i) {
        const int kg = kg0 + 2 * i;
        const float* vq = vp + (size_t)kg * 8 * D_;
        u32x4 pv;
        pv[0] = pk2(vq[0], vq[D_]);
        pv[1] = pk2(vq[2 * D_], vq[3 * D_]);
        pv[2] = pk2(vq[4 * D_], vq[5 * D_]);
        pv[3] = pk2(vq[6 * D_], vq[7 * D_]);
        *(u32x4*)&vtb[dv][(kg ^ (dv & 7)) * 8] = pv;
      }
    }
    __syncthreads();
    f32x4 st[4];
    qkT(st);
#pragma unroll
    for (int nt = 0; nt < 4; ++nt) {
      float w[4];
#pragma unroll
      for (int r = 0; r < 4; ++r) {
        const float pp = __builtin_amdgcn_exp2f(fmaf(st[nt][r], SC2, -MOFF2));
        w[r] = __builtin_amdgcn_exp2f(fmaf(pp, ul2, mcu2));
      }
      Wl += (w[0] + w[1]) + (w[2] + w[3]);
      u32x2 pk;
      pk[0] = pk2(w[0], w[1]);
      pk[1] = pk2(w[2], w[3]);
      *(u32x2*)&wlb[wid][lr][(nt * 8 + lg * 2) ^ ((lr & 7) << 2)] = pk;
    }
#pragma unroll
    for (int ks = 0; ks < 2; ++ks) {
      h16x8 af = H8((const unsigned short*)&wlb[wid][lr][(ks * 16 + lg * 4) ^ ((lr & 7) << 2)]);
#pragma unroll
      for (int dt = 0; dt < 8; ++dt) {
        const int d = dt * 16 + lr;
        h16x8 vf = H8(&vtb[d][((ks * 4 + lg) ^ (d & 7)) * 8]);
        y[dt] = __builtin_amdgcn_mfma_f32_16x16x32_f16(af, vf, y[dt], 0, 0, 0);
      }
    }
  }
  Wl += __shfl_xor(Wl, 16);
  Wl += __shfl_xor(Wl, 32);
  const float winv = 1.0f / Wl;
  float* op = Og + bh + (size_t)(q0 + wid * 16) * D_;
#pragma unroll
  for (int r = 0; r < 4; ++r) {
    const float wv = __shfl(winv, lg * 4 + r);
#pragma unroll
    for (int dt = 0; dt < 8; ++dt)
      op[(size_t)(lg * 4 + r) * D_ + dt * 16 + lr] = y[dt][r] * wv;
  }
}

extern "C" void kernel_launch(void* const* d_in, const int* in_sizes, int n_in,
                              void* d_out, int out_size, void* d_ws, size_t ws_size,
                              hipStream_t stream) {
  (void)in_sizes; (void)n_in; (void)out_size;
  const float* Q = (const float*)d_in[0];
  const float* K = (const float*)d_in[1];
  const float* V = (const float*)d_in[2];
  float* O = (float*)d_out;
  const size_t half = (size_t)NB * NH * T_ * DK * 2;  // 16.78 MB per tensor
  if (ws_size >= 2 * half) {
    unsigned short* K16  = (unsigned short*)d_ws;
    unsigned short* V16t = (unsigned short*)((char*)d_ws + half);
    cvtK16<<<dim3(1024), 256, 0, stream>>>(K, K16);
    trV16<<<dim3(1024), 256, 0, stream>>>(V, V16t);
    simattn_v7<<<dim3(NWG), 256, 0, stream>>>(Q, K16, V16t, O);
  } else {
    simattn_fb<<<dim3(NWG), 256, 0, stream>>>(Q, K, V, O);
  }
}

// Round 8
// 173.094 us; speedup vs baseline: 1.0250x; 1.0250x over previous
//
#include <hip/hip_runtime.h>

// SimAttn: out = softmax(1000*softmax(QK^T/sqrt(dk))) @ V, fp32 I/O.
// v8 = v7 skeleton (pre-converted f16 K [bh][k][d] / transposed V [bh][d][k]
// in d_ws, KB=32 chunks, global_load_lds staging with source-side swizzle,
// double-buffered, one barrier/chunk) with R4's 32x32x16 MFMA geometry:
//   - 128-thread blocks, 2 waves, each wave owns 32 q-rows (BQ=64) -> every
//     K/V LDS byte feeds 2x the q-work of v7 (per-CU LDS volume halves).
//   - QK: A = K tile (LDS), B = Q (regs) -> S^T 32k x 32q, 8 MFMA/chunk.
//   - w: C/D -> A-frag via 2 shfl_xor(32) + selects per k-half (R4-validated).
//   - PV: A = w, B = V^T tile (b128 reads), 8 MFMA/chunk.
// pass 1: row max m, l8 = sum 2^(s*SC2-MOFF2) (fixed stabilizer 8);
// pass 2: identical scores, p = 2^(s*SC2-MOFF2), w = 2^(p*ul2 + mcu2) <= ~1,
//         ul2 = (1000/l8)*log2e, mcu2 = -ul2*pm; normalize by sum(w).

typedef __attribute__((ext_vector_type(4))) float f32x4;
typedef __attribute__((ext_vector_type(16))) float f32x16;
typedef __attribute__((ext_vector_type(8))) _Float16 h16x8;
typedef __attribute__((ext_vector_type(4))) _Float16 h16x4;
typedef __attribute__((ext_vector_type(8))) short s16x8;
typedef __attribute__((ext_vector_type(4))) short s16x4;
typedef __attribute__((ext_vector_type(2))) unsigned int u32x2;
typedef __attribute__((ext_vector_type(4))) unsigned int u32x4;

#define NB 4
#define T_ 2048
#define D_ 1024
#define NH 8
#define DK 128
#define BQ 64
#define NWG (NB * NH * (T_ / BQ))  // 1024
#define KB2 32
#define NKC2 (T_ / KB2)            // 64
#define SCALE 0.08838834764831845f // 1/sqrt(128)
#define SC2   0.12751741689839996f // SCALE * log2(e)
#define MOFF2 11.541560327111707f  // 8 * log2(e)
#define L2E   1.4426950408889634f

__device__ __forceinline__ unsigned int pk2(float a, float b) {
  return __builtin_bit_cast(unsigned int, __builtin_amdgcn_cvt_pkrtz(a, b));
}
#define H8(p) __builtin_bit_cast(h16x8, *(const s16x8*)(p))

__device__ __forceinline__ void gload16(const unsigned short* g, unsigned short* l) {
  __builtin_amdgcn_global_load_lds(
      (const __attribute__((address_space(1))) void*)g,
      (__attribute__((address_space(3))) void*)l, 16, 0, 0);
}

// ---- pre-kernel 1: K fp32 [b][k][h*128+d] -> f16 K16[(b*8+h)][k][d] --------
__global__ __launch_bounds__(256) void cvtK16(const float* __restrict__ Kg,
                                              unsigned short* __restrict__ K16) {
  const int t = threadIdx.x;
#pragma unroll
  for (int i = 0; i < 4; ++i) {
    const unsigned gid = blockIdx.x * 1024u + i * 256u + t;
    const unsigned bhk = gid >> 4, dg = gid & 15u;
    const unsigned b = bhk >> 14, rem = bhk & 16383u;
    const unsigned h = rem >> 11, k = rem & 2047u;
    const float* s = Kg + ((size_t)b * T_ + k) * D_ + h * DK + dg * 8;
    f32x4 x0 = *(const f32x4*)s, x1 = *(const f32x4*)(s + 4);
    h16x8 hv;
#pragma unroll
    for (int j = 0; j < 4; ++j) { hv[j] = (_Float16)x0[j]; hv[j + 4] = (_Float16)x1[j]; }
    *(u32x4*)(K16 + (size_t)gid * 8) = __builtin_bit_cast(u32x4, hv);
  }
}

// ---- pre-kernel 2: V fp32 -> f16 transposed V16t[(b*8+h)][d][k] ------------
__global__ __launch_bounds__(256) void trV16(const float* __restrict__ Vg,
                                             unsigned short* __restrict__ V16t) {
  __shared__ float vt[64][129];
  const int t = threadIdx.x;
  const int bh = blockIdx.x >> 5;
  const int kc = blockIdx.x & 31;
  const int b = bh >> 3, h = bh & 7;
  const float* src = Vg + ((size_t)b * T_ + kc * 64) * D_ + h * DK;
#pragma unroll
  for (int p = 0; p < 8; ++p) {
    const int j = t + p * 256;
    const int row = j >> 5, c4 = j & 31;
    f32x4 v = *(const f32x4*)(src + (size_t)row * D_ + c4 * 4);
#pragma unroll
    for (int i = 0; i < 4; ++i) vt[row][c4 * 4 + i] = v[i];
  }
  __syncthreads();
  unsigned short* dst = V16t + (size_t)bh * DK * T_ + (size_t)kc * 64;
#pragma unroll
  for (int i = 0; i < 4; ++i) {
    const int gg = t + i * 256;
    const int d = gg >> 3, kg = gg & 7;
    u32x4 pv;
#pragma unroll
    for (int jj = 0; jj < 4; ++jj)
      pv[jj] = pk2(vt[kg * 8 + 2 * jj][d], vt[kg * 8 + 2 * jj + 1][d]);
    *(u32x4*)(dst + (size_t)d * T_ + kg * 8) = pv;
  }
}

// ---- main kernel (128 threads = 2 waves, each wave owns 32 q-rows) ---------
__global__ __launch_bounds__(128, 2) void simattn_v8(
    const float* __restrict__ Qg, const unsigned short* __restrict__ K16,
    const unsigned short* __restrict__ V16t, float* __restrict__ Og) {
  __shared__ __align__(16) unsigned short kf[2][KB2 * DK];   // 16 KB
  __shared__ __align__(16) unsigned short vts[2][DK * KB2];  // 16 KB

  const int tid  = threadIdx.x;
  const int wid2 = tid >> 6;      // 0..1
  const int lane = tid & 63;
  const int c    = lane & 31;     // q-col (QK C/D) / d-col (PV B) / k-row (QK A)
  const int g    = lane >> 5;     // half-wave slot group
  const bool hi  = (g != 0);

  // XCD-chunked swizzle (1024 % 8 == 0 -> simple bijection)
  const int blk  = (blockIdx.x & 7) * (NWG >> 3) + (blockIdx.x >> 3);
  const int qblk = blk & (T_ / BQ - 1);
  const int h    = (blk >> 5) & (NH - 1);
  const int b    = blk >> 8;
  const int q0   = qblk * BQ;
  const size_t bh  = (size_t)b * (T_ * D_) + (size_t)h * DK;  // fp32 panels
  const int    bhp = b * NH + h;
  const unsigned short* kp16 = K16 + (size_t)bhp * (T_ * DK);
  const unsigned short* vp16 = V16t + (size_t)bhp * (DK * T_);

  // ---- Q B-frags (f16): lane holds Q[d = step*16 + g*8 + i][q = qw] --------
  h16x8 qf[8];
  {
    const float* qp = Qg + bh + (size_t)(q0 + wid2 * 32 + c) * D_;
#pragma unroll
    for (int step = 0; step < 8; ++step) {
      const int d0 = step * 16 + g * 8;
      f32x4 x0 = *(const f32x4*)(qp + d0);
      f32x4 x1 = *(const f32x4*)(qp + d0 + 4);
#pragma unroll
      for (int i = 0; i < 4; ++i) {
        qf[step][i]     = (_Float16)x0[i];
        qf[step][i + 4] = (_Float16)x1[i];
      }
    }
  }

  // ---- staging source offsets (chunk-invariant) ----------------------------
  // K LDS granule t at row r holds global granule ((t - sk(r)) & 15) ^ (r & 7),
  // sk(r) = 4*((r>>3)&1)  (XOR spread + row-skew -> 2-way max on A reads).
  // V LDS slot t at row d holds global slot t ^ ((d>>1)&3).
  int koffs[4], voffs[4], ldst[4];
#pragma unroll
  for (int i = 0; i < 4; ++i) {
    const int id = wid2 * 4 + i;
    ldst[i] = id * 512 + lane * 8;
    {
      const int r = id * 4 + (lane >> 4), t = lane & 15;
      const int sk = 4 * ((id >> 1) & 1);
      koffs[i] = r * DK + ((((t - sk) & 15) ^ (r & 7)) * 8);
    }
    {
      const int d = id * 16 + (lane >> 2), t = lane & 3;
      voffs[i] = d * T_ + ((t ^ ((d >> 1) & 3)) * 8);
    }
  }
  auto stK = [&](int kc, int buf) {
    const unsigned short* s0 = kp16 + (size_t)kc * (KB2 * DK);
#pragma unroll
    for (int i = 0; i < 4; ++i) gload16(s0 + koffs[i], &kf[buf][ldst[i]]);
  };
  auto stV = [&](int kc, int buf) {
    const unsigned short* s0 = vp16 + kc * KB2;
#pragma unroll
    for (int i = 0; i < 4; ++i) gload16(s0 + voffs[i], &vts[buf][ldst[i]]);
  };

  // K A-frag read offsets (chunk-invariant): row c, granule for step/g.
  int kread[8];
  {
    const int xr = c & 7, skr = 4 * ((c >> 3) & 1);
#pragma unroll
    for (int step = 0; step < 8; ++step)
      kread[step] = c * DK + (((((2 * step + g) ^ xr) + skr) & 15) * 8);
  }
  const int vsw = (c >> 1) & 3;

  // QK^T (swapped): st[r] = S[k = (r&3)+8*(r>>2)+4g][q = c] over the chunk.
  auto qkT = [&](int buf) {
    f32x16 st;
#pragma unroll
    for (int i = 0; i < 16; ++i) st[i] = 0.f;
#pragma unroll
    for (int step = 0; step < 8; ++step) {
      st = __builtin_amdgcn_mfma_f32_32x32x16_f16(H8(&kf[buf][kread[step]]),
                                                  qf[step], st, 0, 0, 0);
    }
    return st;
  };

  // ---- pass 1: per-q max + l8 = sum 2^(s*SC2 - MOFF2) ----------------------
  float msc = -3.0e38f, l8 = 0.f;
  stK(0, 0);
  __syncthreads();
  for (int kc = 0; kc < NKC2; ++kc) {
    if (kc + 1 < NKC2) stK(kc + 1, (kc + 1) & 1);
    f32x16 st = qkT(kc & 1);
    float e[16];
#pragma unroll
    for (int r = 0; r < 16; ++r) {
      msc = fmaxf(msc, st[r]);
      e[r] = __builtin_amdgcn_exp2f(fmaf(st[r], SC2, -MOFF2));
    }
    float s0 = 0.f, s1 = 0.f, s2 = 0.f, s3 = 0.f;
#pragma unroll
    for (int r = 0; r < 4; ++r) {
      s0 += e[r]; s1 += e[4 + r]; s2 += e[8 + r]; s3 += e[12 + r];
    }
    l8 += (s0 + s1) + (s2 + s3);
    __syncthreads();
  }
  msc = fmaxf(msc, __shfl_xor(msc, 32));
  l8 += __shfl_xor(l8, 32);
  const float pm   = __builtin_amdgcn_exp2f(fmaf(msc, SC2, -MOFF2)); // = max p
  const float ul2  = (1000.0f / l8) * L2E;
  const float mcu2 = -ul2 * pm;

  // ---- pass 2: scores -> w (regs, one half-swap) -> PV ---------------------
  f32x16 y[4];
#pragma unroll
  for (int dt = 0; dt < 4; ++dt)
#pragma unroll
    for (int i = 0; i < 16; ++i) y[dt][i] = 0.f;
  float Wl = 0.f;

  stK(0, 0);
  stV(0, 0);
  __syncthreads();
  for (int kc = 0; kc < NKC2; ++kc) {
    if (kc + 1 < NKC2) { stK(kc + 1, (kc + 1) & 1); stV(kc + 1, (kc + 1) & 1); }
    const int buf = kc & 1;
    f32x16 st = qkT(buf);  // bitwise-identical to pass 1

    // weights (q = c, k = (r&3)+8*(r>>2)+4g), packed into 8 dwords pw[r>>1]
    unsigned pw[8];
#pragma unroll
    for (int m = 0; m < 8; ++m) {
      const float p0 = __builtin_amdgcn_exp2f(fmaf(st[2 * m], SC2, -MOFF2));
      const float p1 = __builtin_amdgcn_exp2f(fmaf(st[2 * m + 1], SC2, -MOFF2));
      const float w0 = __builtin_amdgcn_exp2f(fmaf(p0, ul2, mcu2));
      const float w1 = __builtin_amdgcn_exp2f(fmaf(p1, ul2, mcu2));
      Wl += w0 + w1;
      pw[m] = pk2(w0, w1);
    }

    // C/D -> A-frag per k-half hh: A[q=c][k = hh*16 + g*8 + i]
#pragma unroll
    for (int hh = 0; hh < 2; ++hh) {
      const unsigned t0 = hi ? pw[4 * hh] : pw[4 * hh + 2];
      const unsigned t1 = hi ? pw[4 * hh + 1] : pw[4 * hh + 3];
      const unsigned r0 = (unsigned)__shfl_xor((int)t0, 32);
      const unsigned r1 = (unsigned)__shfl_xor((int)t1, 32);
      u32x4 aw;
      aw[0] = hi ? r0 : pw[4 * hh];
      aw[1] = hi ? r1 : pw[4 * hh + 1];
      aw[2] = hi ? pw[4 * hh + 2] : r0;
      aw[3] = hi ? pw[4 * hh + 3] : r1;
      const h16x8 af = __builtin_bit_cast(h16x8, aw);
#pragma unroll
      for (int dt = 0; dt < 4; ++dt) {
        const int d = dt * 32 + c;
        const h16x8 vf = H8(&vts[buf][d * KB2 + (((2 * hh + g) ^ vsw) * 8)]);
        y[dt] = __builtin_amdgcn_mfma_f32_32x32x16_f16(af, vf, y[dt], 0, 0, 0);
      }
    }
    __syncthreads();
  }

  // ---- normalize and store -------------------------------------------------
  Wl += __shfl_xor(Wl, 32);
  const float winv = 1.0f / Wl;  // valid for q = c

  float* ob = Og + bh + (size_t)(q0 + wid2 * 32) * D_;
#pragma unroll
  for (int r = 0; r < 16; ++r) {
    const int qrow = (r & 3) + 8 * (r >> 2) + 4 * g;  // C/D row (verified map)
    const float wv = __shfl(winv, qrow);
#pragma unroll
    for (int dt = 0; dt < 4; ++dt) {
      ob[(size_t)qrow * D_ + dt * 32 + c] = y[dt][r] * wv;
    }
  }
}

// ---- fallback: R3-style kernel (used when ws_size is too small) ------------
__global__ __launch_bounds__(256, 4) void simattn_fb(
    const float* __restrict__ Qg, const float* __restrict__ Kg,
    const float* __restrict__ Vg, float* __restrict__ Og) {
  __shared__ __align__(16) unsigned short kfb[64][DK];
  __shared__ __align__(16) unsigned short vtb[DK][64];
  __shared__ __align__(16) unsigned int   wlb[4][16][32];

  const int tid  = threadIdx.x;
  const int wid  = tid >> 6;
  const int lane = tid & 63;
  const int lr   = lane & 15;
  const int lg   = lane >> 4;

  const int blk  = blockIdx.x;
  const int qblk = blk & (T_ / BQ - 1);
  const int h    = (blk >> 5) & (NH - 1);
  const int b    = blk >> 8;
  const int q0   = qblk * BQ;
  const size_t bh = (size_t)b * (T_ * D_) + (size_t)h * DK;

  h16x8 qf[4];
  {
    const float* qp = Qg + bh + (size_t)(q0 + wid * 16 + lr) * D_;
#pragma unroll
    for (int s = 0; s < 4; ++s) {
      const int d0 = s * 32 + lg * 8;
      f32x4 x0 = *(const f32x4*)(qp + d0);
      f32x4 x1 = *(const f32x4*)(qp + d0 + 4);
#pragma unroll
      for (int i = 0; i < 4; ++i) { qf[s][i] = (_Float16)x0[i]; qf[s][i+4] = (_Float16)x1[i]; }
    }
  }
  auto stageK = [&](int kc) {
    const float* kp = Kg + bh + (size_t)kc * 64 * D_;
#pragma unroll
    for (int p = 0; p < 8; ++p) {
      const int j = tid + p * 256;
      const int row = j >> 5, c4 = j & 31;
      f32x4 v = *(const f32x4*)(kp + (size_t)row * D_ + c4 * 4);
      h16x4 hv;
#pragma unroll
      for (int i = 0; i < 4; ++i) hv[i] = (_Float16)v[i];
      const int e = (c4 * 4) ^ ((row & 7) << 3);
      *(s16x4*)&kfb[row][e] = __builtin_bit_cast(s16x4, hv);
    }
  };
  auto qkT = [&](f32x4* st) {
#pragma unroll
    for (int nt = 0; nt < 4; ++nt) st[nt] = (f32x4){0.f, 0.f, 0.f, 0.f};
#pragma unroll
    for (int s = 0; s < 4; ++s) {
#pragma unroll
      for (int nt = 0; nt < 4; ++nt) {
        const int kr = nt * 16 + lr;
        const int e = (s * 32 + lg * 8) ^ ((kr & 7) << 3);
        st[nt] = __builtin_amdgcn_mfma_f32_16x16x32_f16(H8(&kfb[kr][e]), qf[s], st[nt], 0, 0, 0);
      }
    }
  };
  float msc = -3.0e38f, l8 = 0.f;
  for (int kc = 0; kc < 32; ++kc) {
    __syncthreads();
    stageK(kc);
    __syncthreads();
    f32x4 st[4];
    qkT(st);
#pragma unroll
    for (int nt = 0; nt < 4; ++nt)
#pragma unroll
      for (int r = 0; r < 4; ++r) {
        const float s = st[nt][r];
        msc = fmaxf(msc, s);
        l8 += __builtin_amdgcn_exp2f(fmaf(s, SC2, -MOFF2));
      }
  }
  msc = fmaxf(msc, __shfl_xor(msc, 16));
  msc = fmaxf(msc, __shfl_xor(msc, 32));
  l8 += __shfl_xor(l8, 16);
  l8 += __shfl_xor(l8, 32);
  const float pm   = __builtin_amdgcn_exp2f(fmaf(msc, SC2, -MOFF2));
  const float ul2  = (1000.0f / l8) * L2E;
  const float mcu2 = -ul2 * pm;

  f32x4 y[8];
#pragma unroll
  for (int dt = 0; dt < 8; ++dt) y[dt] = (f32x4){0.f, 0.f, 0.f, 0.f};
  float Wl = 0.f;
  const int dv  = tid & 127;
  const int kg0 = tid >> 7;
  for (int kc = 0; kc < 32; ++kc) {
    __syncthreads();
    stageK(kc);
    {
      const float* vp = Vg + bh + (size_t)kc * 64 * D_ + dv;
#pragma unroll
      for (int i = 0; i < 4; ++i) {
        const int kg = kg0 + 2 * i;
        const float* vq = vp + (size_t)kg * 8 * D_;
        u32x4 pv;
        pv[0] = pk2(vq[0], vq[D_]);
        pv[1] = pk2(vq[2 * D_], vq[3 * D_]);
        pv[2] = pk2(vq[4 * D_], vq[5 * D_]);
        pv[3] = pk2(vq[6 * D_], vq[7 * D_]);
        *(u32x4*)&vtb[dv][(kg ^ (dv & 7)) * 8] = pv;
      }
    }
    __syncthreads();
    f32x4 st[4];
    qkT(st);
#pragma unroll
    for (int nt = 0; nt < 4; ++nt) {
      float w[4];
#pragma unroll
      for (int r = 0; r < 4; ++r) {
        const float pp = __builtin_amdgcn_exp2f(fmaf(st[nt][r], SC2, -MOFF2));
        w[r] = __builtin_amdgcn_exp2f(fmaf(pp, ul2, mcu2));
      }
      Wl += (w[0] + w[1]) + (w[2] + w[3]);
      u32x2 pk;
      pk[0] = pk2(w[0], w[1]);
      pk[1] = pk2(w[2], w[3]);
      *(u32x2*)&wlb[wid][lr][(nt * 8 + lg * 2) ^ ((lr & 7) << 2)] = pk;
    }
#pragma unroll
    for (int ks = 0; ks < 2; ++ks) {
      h16x8 af = H8((const unsigned short*)&wlb[wid][lr][(ks * 16 + lg * 4) ^ ((lr & 7) << 2)]);
#pragma unroll
      for (int dt = 0; dt < 8; ++dt) {
        const int d = dt * 16 + lr;
        h16x8 vf = H8(&vtb[d][((ks * 4 + lg) ^ (d & 7)) * 8]);
        y[dt] = __builtin_amdgcn_mfma_f32_16x16x32_f16(af, vf, y[dt], 0, 0, 0);
      }
    }
  }
  Wl += __shfl_xor(Wl, 16);
  Wl += __shfl_xor(Wl, 32);
  const float winv = 1.0f / Wl;
  float* op = Og + bh + (size_t)(q0 + wid * 16) * D_;
#pragma unroll
  for (int r = 0; r < 4; ++r) {
    const float wv = __shfl(winv, lg * 4 + r);
#pragma unroll
    for (int dt = 0; dt < 8; ++dt)
      op[(size_t)(lg * 4 + r) * D_ + dt * 16 + lr] = y[dt][r] * wv;
  }
}

extern "C" void kernel_launch(void* const* d_in, const int* in_sizes, int n_in,
                              void* d_out, int out_size, void* d_ws, size_t ws_size,
                              hipStream_t stream) {
  (void)in_sizes; (void)n_in; (void)out_size;
  const float* Q = (const float*)d_in[0];
  const float* K = (const float*)d_in[1];
  const float* V = (const float*)d_in[2];
  float* O = (float*)d_out;
  const size_t half = (size_t)NB * NH * T_ * DK * 2;  // 16.78 MB per tensor
  if (ws_size >= 2 * half) {
    unsigned short* K16  = (unsigned short*)d_ws;
    unsigned short* V16t = (unsigned short*)((char*)d_ws + half);
    cvtK16<<<dim3(1024), 256, 0, stream>>>(K, K16);
    trV16<<<dim3(1024), 256, 0, stream>>>(V, V16t);
    simattn_v8<<<dim3(NWG), 128, 0, stream>>>(Q, K16, V16t, O);
  } else {
    simattn_fb<<<dim3(NWG), 256, 0, stream>>>(Q, K, V, O);
  }
}